// Round 1
// baseline (284.616 us; speedup 1.0000x reference)
//
#include <hip/hip_runtime.h>
#include <math.h>

#define BSZ 8
#define SEQ 2048
#define EMB 1024
#define HD  64
#define NROWS (BSZ*SEQ)   // 16384

// ---------------- QKV projection ----------------
// grid 256, block 256. Each block: 64 rows x (3x64) cols, K loop over 1024.
#define PBM 64
#define PBK 32
#define XPAD 68           // padded LDS stride (multiple of 4 floats, not mult of 32)

__global__ __launch_bounds__(256) void qkv_proj_kernel(
    const float* __restrict__ x,
    const float* __restrict__ Wq,
    const float* __restrict__ Wk,
    const float* __restrict__ Wv,
    float* __restrict__ qo,
    float* __restrict__ ko,
    float* __restrict__ vo)
{
    __shared__ float xs[PBK][XPAD];   // transposed x tile: xs[k][row]
    __shared__ float ws[PBK][192];    // [k][col]: 0..63 Wq, 64..127 Wk, 128..191 Wv

    const int tid = threadIdx.x;
    const int ty = tid >> 4;   // 0..15 row group (4 rows each)
    const int tx = tid & 15;   // 0..15 col group (4 cols per proj each)
    const int row0 = blockIdx.x * PBM;

    float acc[3][4][4];
#pragma unroll
    for (int m = 0; m < 3; ++m)
#pragma unroll
        for (int r = 0; r < 4; ++r)
#pragma unroll
            for (int c = 0; c < 4; ++c) acc[m][r][c] = 0.f;

    for (int k0 = 0; k0 < EMB; k0 += PBK) {
        // stage x tile (64 rows x 32 k), store transposed
#pragma unroll
        for (int i = 0; i < 2; ++i) {
            int idx = tid + i * 256;      // float4 index 0..511
            int r  = idx >> 3;            // 8 float4 per row
            int c4 = idx & 7;
            float4 xv = *(const float4*)(x + (size_t)(row0 + r) * EMB + k0 + c4 * 4);
            xs[c4 * 4 + 0][r] = xv.x;
            xs[c4 * 4 + 1][r] = xv.y;
            xs[c4 * 4 + 2][r] = xv.z;
            xs[c4 * 4 + 3][r] = xv.w;
        }
        // stage W tiles (32 x 64 each)
#pragma unroll
        for (int m = 0; m < 3; ++m) {
            const float* W = (m == 0) ? Wq : (m == 1) ? Wk : Wv;
#pragma unroll
            for (int i = 0; i < 2; ++i) {
                int idx = tid + i * 256;  // 0..511
                int r  = idx >> 4;        // 16 float4 per row
                int c4 = idx & 15;
                *(float4*)&ws[r][m * 64 + c4 * 4] =
                    *(const float4*)(W + (size_t)(k0 + r) * HD + c4 * 4);
            }
        }
        __syncthreads();
#pragma unroll
        for (int kk = 0; kk < PBK; ++kk) {
            float4 xv = *(const float4*)&xs[kk][ty * 4];
            float4 w0 = *(const float4*)&ws[kk][tx * 4];
            float4 w1 = *(const float4*)&ws[kk][64 + tx * 4];
            float4 w2 = *(const float4*)&ws[kk][128 + tx * 4];
            float xr[4] = {xv.x, xv.y, xv.z, xv.w};
            float wa[4] = {w0.x, w0.y, w0.z, w0.w};
            float wb[4] = {w1.x, w1.y, w1.z, w1.w};
            float wc[4] = {w2.x, w2.y, w2.z, w2.w};
#pragma unroll
            for (int r = 0; r < 4; ++r) {
#pragma unroll
                for (int c = 0; c < 4; ++c) {
                    acc[0][r][c] += xr[r] * wa[c];
                    acc[1][r][c] += xr[r] * wb[c];
                    acc[2][r][c] += xr[r] * wc[c];
                }
            }
        }
        __syncthreads();
    }
    // write out
#pragma unroll
    for (int m = 0; m < 3; ++m) {
        float* dst = (m == 0) ? qo : (m == 1) ? ko : vo;
#pragma unroll
        for (int r = 0; r < 4; ++r) {
            float4 val;
            val.x = acc[m][r][0]; val.y = acc[m][r][1];
            val.z = acc[m][r][2]; val.w = acc[m][r][3];
            *(float4*)(dst + (size_t)(row0 + ty * 4 + r) * HD + tx * 4) = val;
        }
    }
}

// ---------------- Flash attention (causal, fp32) ----------------
// QT=KT=32. Pair q-tile i with 63-i -> every block does exactly 65 k-steps.
// grid = 8 batches * 32 pairs = 256 blocks, 256 threads.
#define QT 32
#define KT 32
#define SPAD 68   // padded stride for Q/K/V tiles
#define PPAD 36   // padded stride for P tile

__global__ __launch_bounds__(256) void attn_kernel(
    const float* __restrict__ q,
    const float* __restrict__ kg,
    const float* __restrict__ vg,
    float* __restrict__ out)
{
    __shared__ float Qs[QT][SPAD];
    __shared__ float Ks[KT][SPAD];
    __shared__ float Vs[KT][SPAD];
    __shared__ float Ps[QT][PPAD];

    const int bid = blockIdx.x;
    const int b  = bid >> 5;      // batch
    const int pi = bid & 31;      // pair index
    const int tiles[2] = {pi, 63 - pi};

    const float* qb = q  + (size_t)b * SEQ * HD;
    const float* kb = kg + (size_t)b * SEQ * HD;
    const float* vb = vg + (size_t)b * SEQ * HD;
    float* ob = out + (size_t)b * SEQ * HD;

    const int tid = threadIdx.x;
    const int ty = tid >> 4;   // 0..15 -> rows ty*2, ty*2+1
    const int tx = tid & 15;   // 0..15 -> score cols tx*2.. / out cols tx*4..

    const float sc = 0.125f;   // 1/sqrt(64)

    for (int ph = 0; ph < 2; ++ph) {
        const int qt = tiles[ph];
        __syncthreads();   // protect Qs/Ks/Vs/Ps from previous phase readers
        // stage Q tile (32 x 64)
#pragma unroll
        for (int i = 0; i < 2; ++i) {
            int idx = tid + i * 256;
            int r = idx >> 4, c4 = idx & 15;
            *(float4*)&Qs[r][c4 * 4] =
                *(const float4*)(qb + (size_t)(qt * QT + r) * HD + c4 * 4);
        }
        float m0 = -1e30f, m1 = -1e30f;
        float l0 = 0.f, l1 = 0.f;
        float o0[4] = {0.f, 0.f, 0.f, 0.f};
        float o1[4] = {0.f, 0.f, 0.f, 0.f};
        __syncthreads();

        for (int kt = 0; kt <= qt; ++kt) {
            // stage K,V tiles
#pragma unroll
            for (int i = 0; i < 2; ++i) {
                int idx = tid + i * 256;
                int r = idx >> 4, c4 = idx & 15;
                *(float4*)&Ks[r][c4 * 4] =
                    *(const float4*)(kb + (size_t)(kt * KT + r) * HD + c4 * 4);
                *(float4*)&Vs[r][c4 * 4] =
                    *(const float4*)(vb + (size_t)(kt * KT + r) * HD + c4 * 4);
            }
            __syncthreads();

            // GEMM1: S = Q K^T (2x2 per thread)
            float s00 = 0.f, s01 = 0.f, s10 = 0.f, s11 = 0.f;
#pragma unroll
            for (int h4 = 0; h4 < 16; ++h4) {
                float4 q0 = *(const float4*)&Qs[ty * 2 + 0][h4 * 4];
                float4 q1 = *(const float4*)&Qs[ty * 2 + 1][h4 * 4];
                float4 c0 = *(const float4*)&Ks[tx * 2 + 0][h4 * 4];
                float4 c1 = *(const float4*)&Ks[tx * 2 + 1][h4 * 4];
                s00 += q0.x*c0.x + q0.y*c0.y + q0.z*c0.z + q0.w*c0.w;
                s01 += q0.x*c1.x + q0.y*c1.y + q0.z*c1.z + q0.w*c1.w;
                s10 += q1.x*c0.x + q1.y*c0.y + q1.z*c0.z + q1.w*c0.w;
                s11 += q1.x*c1.x + q1.y*c1.y + q1.z*c1.z + q1.w*c1.w;
            }
            s00 *= sc; s01 *= sc; s10 *= sc; s11 *= sc;
            if (kt == qt) {   // diagonal tile: causal mask
                int r0 = ty * 2, r1 = ty * 2 + 1;
                int c0i = tx * 2, c1i = tx * 2 + 1;
                if (c0i > r0) s00 = -1e30f;
                if (c1i > r0) s01 = -1e30f;
                if (c0i > r1) s10 = -1e30f;
                if (c1i > r1) s11 = -1e30f;
            }

            // online softmax update (stats replicated across the 16 lanes of a row group)
            float rm0 = fmaxf(s00, s01), rm1 = fmaxf(s10, s11);
#pragma unroll
            for (int msk = 1; msk < 16; msk <<= 1) {
                rm0 = fmaxf(rm0, __shfl_xor(rm0, msk, 64));
                rm1 = fmaxf(rm1, __shfl_xor(rm1, msk, 64));
            }
            float mn0 = fmaxf(m0, rm0), mn1 = fmaxf(m1, rm1);
            float a0 = __expf(m0 - mn0), a1 = __expf(m1 - mn1);
            float p00 = __expf(s00 - mn0), p01 = __expf(s01 - mn0);
            float p10 = __expf(s10 - mn1), p11 = __expf(s11 - mn1);
            float rs0 = p00 + p01, rs1 = p10 + p11;
#pragma unroll
            for (int msk = 1; msk < 16; msk <<= 1) {
                rs0 += __shfl_xor(rs0, msk, 64);
                rs1 += __shfl_xor(rs1, msk, 64);
            }
            l0 = l0 * a0 + rs0;
            l1 = l1 * a1 + rs1;
            m0 = mn0; m1 = mn1;
#pragma unroll
            for (int c = 0; c < 4; ++c) { o0[c] *= a0; o1[c] *= a1; }

            Ps[ty * 2 + 0][tx * 2 + 0] = p00;
            Ps[ty * 2 + 0][tx * 2 + 1] = p01;
            Ps[ty * 2 + 1][tx * 2 + 0] = p10;
            Ps[ty * 2 + 1][tx * 2 + 1] = p11;
            __syncthreads();

            // GEMM2: O += P V  (2 rows x 4 cols per thread)
#pragma unroll
            for (int k4 = 0; k4 < 8; ++k4) {
                float4 p0 = *(const float4*)&Ps[ty * 2 + 0][k4 * 4];
                float4 p1 = *(const float4*)&Ps[ty * 2 + 1][k4 * 4];
                float4 v0 = *(const float4*)&Vs[k4 * 4 + 0][tx * 4];
                float4 v1 = *(const float4*)&Vs[k4 * 4 + 1][tx * 4];
                float4 v2 = *(const float4*)&Vs[k4 * 4 + 2][tx * 4];
                float4 v3 = *(const float4*)&Vs[k4 * 4 + 3][tx * 4];
                o0[0] += p0.x*v0.x + p0.y*v1.x + p0.z*v2.x + p0.w*v3.x;
                o0[1] += p0.x*v0.y + p0.y*v1.y + p0.z*v2.y + p0.w*v3.y;
                o0[2] += p0.x*v0.z + p0.y*v1.z + p0.z*v2.z + p0.w*v3.z;
                o0[3] += p0.x*v0.w + p0.y*v1.w + p0.z*v2.w + p0.w*v3.w;
                o1[0] += p1.x*v0.x + p1.y*v1.x + p1.z*v2.x + p1.w*v3.x;
                o1[1] += p1.x*v0.y + p1.y*v1.y + p1.z*v2.y + p1.w*v3.y;
                o1[2] += p1.x*v0.z + p1.y*v1.z + p1.z*v2.z + p1.w*v3.z;
                o1[3] += p1.x*v0.w + p1.y*v1.w + p1.z*v2.w + p1.w*v3.w;
            }
            __syncthreads();   // protect Ks/Vs/Ps before next iteration's staging
        }

        // normalize + write
        float inv0 = 1.f / l0, inv1 = 1.f / l1;
        float4 r0, r1;
        r0.x = o0[0]*inv0; r0.y = o0[1]*inv0; r0.z = o0[2]*inv0; r0.w = o0[3]*inv0;
        r1.x = o1[0]*inv1; r1.y = o1[1]*inv1; r1.z = o1[2]*inv1; r1.w = o1[3]*inv1;
        *(float4*)(ob + (size_t)(qt * QT + ty * 2 + 0) * HD + tx * 4) = r0;
        *(float4*)(ob + (size_t)(qt * QT + ty * 2 + 1) * HD + tx * 4) = r1;
    }
}

extern "C" void kernel_launch(void* const* d_in, const int* in_sizes, int n_in,
                              void* d_out, int out_size, void* d_ws, size_t ws_size,
                              hipStream_t stream) {
    const float* x  = (const float*)d_in[0];
    const float* Wq = (const float*)d_in[1];
    const float* Wk = (const float*)d_in[2];
    const float* Wv = (const float*)d_in[3];
    float* out = (float*)d_out;

    float* qw = (float*)d_ws;                 // [16384][64]
    float* kw = qw + (size_t)NROWS * HD;
    float* vw = kw + (size_t)NROWS * HD;

    qkv_proj_kernel<<<NROWS / PBM, 256, 0, stream>>>(x, Wq, Wk, Wv, qw, kw, vw);
    attn_kernel<<<256, 256, 0, stream>>>(qw, kw, vw, out);
}

// Round 2
// 109.275 us; speedup vs baseline: 2.6046x; 2.6046x over previous
//
#include <hip/hip_runtime.h>
#include <math.h>

typedef __attribute__((ext_vector_type(8))) short bf16x8;
typedef __attribute__((ext_vector_type(16))) float fx16;

#define SEQ 2048
#define HD 64

// ---------- helpers ----------
__device__ __forceinline__ unsigned f2bf_bits(float f){
  unsigned u = __float_as_uint(f);
  return (u + 0x7fffu + ((u >> 16) & 1u)) >> 16;   // RNE to bf16
}
__device__ __forceinline__ unsigned cvt_pk_bf16(float a, float b){
  unsigned r;
  asm("v_cvt_pk_bf16_f32 %0, %1, %2" : "=v"(r) : "v"(a), "v"(b));
  return r;  // [15:0]=bf16(a), [31:16]=bf16(b)
}
union U8 { bf16x8 v; short s[8]; unsigned u[4]; };

__device__ __forceinline__ fx16 mfma_bf16(bf16x8 a, bf16x8 b, fx16 c){
  return __builtin_amdgcn_mfma_f32_32x32x16_bf16(a, b, c, 0, 0, 0);
}
__device__ __forceinline__ fx16 fzero(){
  fx16 z;
#pragma unroll
  for (int i = 0; i < 16; ++i) z[i] = 0.f;
  return z;
}

// ---------- W convert/transpose/split: wt[n][k], n: 0-63 Wq, 64-127 Wk, 128-191 Wv ----------
__global__ __launch_bounds__(256) void wconv_kernel(
    const float* __restrict__ Wq, const float* __restrict__ Wk, const float* __restrict__ Wv,
    short* __restrict__ wth, short* __restrict__ wtl)
{
  int n = blockIdx.x;              // 0..191
  int mat = n >> 6, col = n & 63;
  const float* W = (mat == 0) ? Wq : (mat == 1) ? Wk : Wv;
  for (int k = threadIdx.x; k < 1024; k += 256) {
    float f = W[(size_t)k * 64 + col];
    unsigned hb = f2bf_bits(f);
    float hf = __uint_as_float(hb << 16);
    unsigned lb = f2bf_bits(f - hf);
    wth[(size_t)n * 1024 + k] = (short)hb;
    wtl[(size_t)n * 1024 + k] = (short)lb;
  }
}

// ---------- QKV projection: MFMA split-bf16 ----------
// grid 256 (64 rows each), 256 threads (4 waves). Tiles 32x32; wave w: m=w&1, n-tiles nset..nset+2.
__global__ __launch_bounds__(256) void proj_kernel(
    const float* __restrict__ x, const short* __restrict__ wth, const short* __restrict__ wtl,
    short* __restrict__ qh, short* __restrict__ ql,
    short* __restrict__ kh, short* __restrict__ kl,
    short* __restrict__ vth, short* __restrict__ vtl)
{
  __shared__ short Xs[64 * 128];   // row s: bytes [0..127]=hi(64 k), [128..255]=lo; XOR-swizzled
  __shared__ short Ws[192 * 128];  // row n: same layout over k
  __shared__ float Vb[64 * 68];    // v transpose bounce

  const int tid = threadIdx.x;
  const int lane = tid & 63, w = tid >> 6;
  const int l31 = lane & 31, h = lane >> 5;
  const int m = w & 1;
  const int nset = (w >> 1) * 3;
  const int row0 = blockIdx.x * 64;

  fx16 accP[3], accQ[3];
#pragma unroll
  for (int t = 0; t < 3; ++t) { accP[t] = fzero(); accQ[t] = fzero(); }

  const int xrow = tid >> 2;
  const int xkc = (tid & 3) * 16;
  const int xswz = (xrow & 7) << 4;

  for (int k0 = 0; k0 < 1024; k0 += 64) {
    // stage x (fp32 -> hi/lo bf16)
    float xf[16];
    {
      float4 a = *(const float4*)(x + (size_t)(row0 + xrow) * 1024 + k0 + xkc + 0);
      float4 b = *(const float4*)(x + (size_t)(row0 + xrow) * 1024 + k0 + xkc + 4);
      float4 c = *(const float4*)(x + (size_t)(row0 + xrow) * 1024 + k0 + xkc + 8);
      float4 d = *(const float4*)(x + (size_t)(row0 + xrow) * 1024 + k0 + xkc + 12);
      xf[0]=a.x; xf[1]=a.y; xf[2]=a.z; xf[3]=a.w;
      xf[4]=b.x; xf[5]=b.y; xf[6]=b.z; xf[7]=b.w;
      xf[8]=c.x; xf[9]=c.y; xf[10]=c.z; xf[11]=c.w;
      xf[12]=d.x; xf[13]=d.y; xf[14]=d.z; xf[15]=d.w;
    }
    U8 xh0, xh1, xl0, xl1;
#pragma unroll
    for (int i = 0; i < 16; ++i) {
      unsigned hb = f2bf_bits(xf[i]);
      float hf = __uint_as_float(hb << 16);
      unsigned lb = f2bf_bits(xf[i] - hf);
      if (i < 8) { xh0.s[i] = (short)hb; xl0.s[i] = (short)lb; }
      else       { xh1.s[i - 8] = (short)hb; xl1.s[i - 8] = (short)lb; }
    }
    {
      char* rp = (char*)Xs + xrow * 256;
      *(bf16x8*)(rp + (( 2 * xkc      ) ^ xswz)) = xh0.v;
      *(bf16x8*)(rp + (( 2 * xkc + 16 ) ^ xswz)) = xh1.v;
      *(bf16x8*)(rp + 128 + (( 2 * xkc      ) ^ xswz)) = xl0.v;
      *(bf16x8*)(rp + 128 + (( 2 * xkc + 16 ) ^ xswz)) = xl1.v;
    }
    // stage W chunk (already bf16 hi/lo, pre-swizzled source)
#pragma unroll
    for (int jj = 0; jj < 12; ++jj) {
      int idx = jj * 256 + tid;
      int wrow = idx >> 4, slot = idx & 15;
      int half = slot >> 3, sb = (slot & 7) << 4;
      int srcb = sb ^ ((wrow & 7) << 4);
      const short* src = (half ? wtl : wth) + (size_t)wrow * 1024 + k0 + (srcb >> 1);
      bf16x8 v = *(const bf16x8*)src;
      *(bf16x8*)((char*)Ws + wrow * 256 + half * 128 + sb) = v;
    }
    __syncthreads();
#pragma unroll
    for (int ks = 0; ks < 4; ++ks) {
      const char* arow = (const char*)Xs + (m * 32 + l31) * 256;
      const int sw = (l31 & 7) << 4;
      const int kb = ks * 32 + 16 * h;
      bf16x8 ah = *(const bf16x8*)(arow + (kb ^ sw));
      bf16x8 al = *(const bf16x8*)(arow + 128 + (kb ^ sw));
#pragma unroll
      for (int t = 0; t < 3; ++t) {
        int n = (nset + t) * 32 + l31;
        const char* brow = (const char*)Ws + n * 256;
        const int swb = (n & 7) << 4;
        bf16x8 bh = *(const bf16x8*)(brow + (kb ^ swb));
        bf16x8 bl = *(const bf16x8*)(brow + 128 + (kb ^ swb));
        accP[t] = mfma_bf16(ah, bh, accP[t]);
        accQ[t] = mfma_bf16(ah, bl, accQ[t]);
        accQ[t] = mfma_bf16(al, bh, accQ[t]);
      }
    }
    __syncthreads();
  }

  // epilogue: q,k direct hi/lo stores; v via LDS transpose bounce
#pragma unroll
  for (int t = 0; t < 3; ++t) {
    int nt = nset + t;
    int mat = nt >> 1;
    int colb = (nt & 1) * 32 + l31;
    if (mat < 2) {
      short* dh = (mat == 0) ? qh : kh;
      short* dl = (mat == 0) ? ql : kl;
#pragma unroll
      for (int r = 0; r < 16; ++r) {
        float f = accP[t][r] + accQ[t][r];
        int rowg = row0 + m * 32 + (r & 3) + 8 * (r >> 2) + 4 * h;
        unsigned hb = f2bf_bits(f);
        float hf = __uint_as_float(hb << 16);
        unsigned lb = f2bf_bits(f - hf);
        dh[(size_t)rowg * 64 + colb] = (short)hb;
        dl[(size_t)rowg * 64 + colb] = (short)lb;
      }
    } else {
#pragma unroll
      for (int r = 0; r < 16; ++r) {
        float f = accP[t][r] + accQ[t][r];
        int srel = m * 32 + (r & 3) + 8 * (r >> 2) + 4 * h;
        Vb[srel * 68 + (nt - 4) * 32 + l31] = f;
      }
    }
  }
  __syncthreads();
  {
    int d = tid >> 2, sc = (tid & 3) * 16;
    int b = row0 >> 11, s0 = row0 & 2047;
    U8 hv0, hv1, lv0, lv1;
#pragma unroll
    for (int ss = 0; ss < 16; ++ss) {
      float f = Vb[(sc + ss) * 68 + d];
      unsigned hb = f2bf_bits(f);
      float hf = __uint_as_float(hb << 16);
      unsigned lb = f2bf_bits(f - hf);
      if (ss < 8) { hv0.s[ss] = (short)hb; lv0.s[ss] = (short)lb; }
      else        { hv1.s[ss - 8] = (short)hb; lv1.s[ss - 8] = (short)lb; }
    }
    size_t o = (size_t)(b * 64 + d) * 2048 + s0 + sc;
    *(bf16x8*)(vth + o) = hv0.v;  *(bf16x8*)(vth + o + 8) = hv1.v;
    *(bf16x8*)(vtl + o) = lv0.v;  *(bf16x8*)(vtl + o + 8) = lv1.v;
  }
}

// ---------- Flash attention, swapped QK^T (S^T = K Q^T), O^T = V^T P^T ----------
// grid 8*80=640 blocks (per-q-tile chunks <=8 k-steps), 256 thr (4 waves): wave w: mk=w>>1, nq=w&1.
__global__ __launch_bounds__(256, 2) void attn_kernel(
    const short* __restrict__ qh, const short* __restrict__ ql,
    const short* __restrict__ kh, const short* __restrict__ kl,
    const short* __restrict__ vth, const short* __restrict__ vtl,
    float* __restrict__ segO, float* __restrict__ segL, float* __restrict__ segM)
{
  __shared__ short Kbuf[2][64 * 128];   // row=k-row: [hi 64 d | lo 64 d], XOR-swizzled
  __shared__ short Vbuf[2][64 * 128];   // row=d:     [hi 64 k | lo 64 k], XOR-swizzled
  __shared__ float Red[2][64];

  const int bid = blockIdx.x;
  const int b = bid / 80;
  int j = bid % 80;
  int g4 = (j < 8) ? 0 : ((j < 24) ? 1 : ((j < 48) ? 2 : 3));
  int base4 = (g4 == 0) ? 0 : (g4 == 1) ? 8 : (g4 == 2) ? 24 : 48;
  int within = j - base4;
  int nch = g4 + 1;
  int qt = g4 * 8 + within / nch;
  int ch = within - (within / nch) * nch;
  int S = qt + 1, bs = S / nch, rem = S - bs * nch;
  int nsteps = bs + (ch < rem ? 1 : 0);
  int kt0 = ch * bs + (ch < rem ? ch : rem);

  const int tid = threadIdx.x;
  const int lane = tid & 63, w = tid >> 6;
  const int mk = w >> 1, nq = w & 1;
  const int l31 = lane & 31, h = lane >> 5;

  // Q B-frags (hoisted, from global; B[k=d][col=q] = Q[q][d])
  bf16x8 qf[2][4];
  {
    size_t qrow = ((size_t)b * 2048 + qt * 64 + nq * 32 + l31) * 64;
#pragma unroll
    for (int ds = 0; ds < 4; ++ds) {
      qf[0][ds] = *(const bf16x8*)(qh + qrow + ds * 16 + 8 * h);
      qf[1][ds] = *(const bf16x8*)(ql + qrow + ds * 16 + 8 * h);
    }
  }

  // staging constants: idx = jj*256+tid -> row = (tid>>4)+16*jj, slot = tid&15
  const int slot = tid & 15;
  const int half = slot >> 3;
  const int sb = (slot & 7) << 4;
  const int rbase = tid >> 4;
  const int d0 = (sb ^ ((rbase & 7) << 4)) >> 1;   // pre-swizzled source offset (shorts)
  const short* ksrc = half ? kl : kh;
  const short* vsrc = half ? vtl : vth;
  const int woff = rbase * 256 + half * 128 + sb;  // LDS write byte offset (+ jj*4096)

  fx16 stA, stB, stC, accA0, accA1, accB0, accB1;
  accA0 = fzero(); accA1 = fzero(); accB0 = fzero(); accB1 = fzero();
  float Mrun = -3e38f, lrun = 0.f;

  bf16x8 kreg[4], vreg[4];
#pragma unroll
  for (int jj = 0; jj < 4; ++jj) {
    kreg[jj] = *(const bf16x8*)(ksrc + ((size_t)b * 2048 + (size_t)kt0 * 64 + rbase + 16 * jj) * 64 + d0);
    vreg[jj] = *(const bf16x8*)(vsrc + ((size_t)(b * 64 + rbase + 16 * jj)) * 2048 + kt0 * 64 + d0);
  }
#pragma unroll
  for (int jj = 0; jj < 4; ++jj) {
    *(bf16x8*)((char*)Kbuf[0] + woff + jj * 4096) = kreg[jj];
    *(bf16x8*)((char*)Vbuf[0] + woff + jj * 4096) = vreg[jj];
  }
  __syncthreads();

  for (int it = 0; it < nsteps; ++it) {
    const int kt = kt0 + it;
    const int p = it & 1;
    const bool hasnext = (it + 1 < nsteps);
    if (hasnext) {
      int kn = kt + 1;
#pragma unroll
      for (int jj = 0; jj < 4; ++jj) {
        kreg[jj] = *(const bf16x8*)(ksrc + ((size_t)b * 2048 + (size_t)kn * 64 + rbase + 16 * jj) * 64 + d0);
        vreg[jj] = *(const bf16x8*)(vsrc + ((size_t)(b * 64 + rbase + 16 * jj)) * 2048 + kn * 64 + d0);
      }
    }
    // QK^T (swapped): S^T tile (mk, nq); A = K rows, B = Q frags
    stA = fzero(); stB = fzero(); stC = fzero();
    {
      const char* arow = (const char*)Kbuf[p] + (mk * 32 + l31) * 256;
      const int sw = (l31 & 7) << 4;
#pragma unroll
      for (int ds = 0; ds < 4; ++ds) {
        const int kb = ds * 32 + 16 * h;
        bf16x8 ah = *(const bf16x8*)(arow + (kb ^ sw));
        bf16x8 al = *(const bf16x8*)(arow + 128 + (kb ^ sw));
        stA = mfma_bf16(ah, qf[0][ds], stA);
        stB = mfma_bf16(ah, qf[1][ds], stB);
        stC = mfma_bf16(al, qf[0][ds], stC);
      }
    }
    float sv[16];
#pragma unroll
    for (int r = 0; r < 16; ++r) {
      float s = (stA[r] + stB[r] + stC[r]) * 0.125f;
      if (kt == qt) {
        int krel = (r & 3) + 8 * (r >> 2) + 4 * h;
        if (mk * 32 + krel > nq * 32 + l31) s = -3e38f;
      }
      sv[r] = s;
    }
    float tm = sv[0];
#pragma unroll
    for (int r = 1; r < 16; ++r) tm = fmaxf(tm, sv[r]);
    tm = fmaxf(tm, __shfl_xor(tm, 32, 64));
    if (lane < 32) Red[mk][nq * 32 + l31] = tm;
    __syncthreads();                         // mid barrier
    float om = Red[mk ^ 1][nq * 32 + l31];
    if (hasnext) {
#pragma unroll
      for (int jj = 0; jj < 4; ++jj) {
        *(bf16x8*)((char*)Kbuf[p ^ 1] + woff + jj * 4096) = kreg[jj];
        *(bf16x8*)((char*)Vbuf[p ^ 1] + woff + jj * 4096) = vreg[jj];
      }
    }
    float Mnew = fmaxf(fmaxf(tm, om), Mrun);
    float alpha = __expf(Mrun - Mnew);
    Mrun = Mnew;
    float pvv[16]; float psum = 0.f;
#pragma unroll
    for (int r = 0; r < 16; ++r) { pvv[r] = __expf(sv[r] - Mnew); psum += pvv[r]; }
    psum += __shfl_xor(psum, 32, 64);
    lrun = lrun * alpha + psum;
#pragma unroll
    for (int r = 0; r < 16; ++r) { accA0[r] *= alpha; accA1[r] *= alpha; accB0[r] *= alpha; accB1[r] *= alpha; }
    // P -> bf16 hi/lo packed dwords
    unsigned chv[8], clv[8];
#pragma unroll
    for (int q2 = 0; q2 < 8; ++q2) {
      unsigned c = cvt_pk_bf16(pvv[2 * q2], pvv[2 * q2 + 1]);
      chv[q2] = c;
      float f0 = __uint_as_float(c << 16);
      float f1 = __uint_as_float(c & 0xffff0000u);
      clv[q2] = cvt_pk_bf16(pvv[2 * q2] - f0, pvv[2 * q2 + 1] - f1);
    }
    // PV: O^T tiles (md, nq); A = V^T rows from LDS, B = P^T frags assembled in-register
#pragma unroll
    for (int kp = 0; kp < 2; ++kp) {
      U8 ph, pl;
      {
        unsigned c0 = chv[4 * kp], c1 = chv[4 * kp + 1], c2 = chv[4 * kp + 2], c3 = chv[4 * kp + 3];
        unsigned x0 = (unsigned)__shfl_xor((int)c0, 32, 64);
        unsigned x1 = (unsigned)__shfl_xor((int)c1, 32, 64);
        unsigned x2 = (unsigned)__shfl_xor((int)c2, 32, 64);
        unsigned x3 = (unsigned)__shfl_xor((int)c3, 32, 64);
        ph.u[0] = h ? x2 : c0;  ph.u[1] = h ? x3 : c1;
        ph.u[2] = h ? c2 : x0;  ph.u[3] = h ? c3 : x1;
        c0 = clv[4 * kp]; c1 = clv[4 * kp + 1]; c2 = clv[4 * kp + 2]; c3 = clv[4 * kp + 3];
        x0 = (unsigned)__shfl_xor((int)c0, 32, 64);
        x1 = (unsigned)__shfl_xor((int)c1, 32, 64);
        x2 = (unsigned)__shfl_xor((int)c2, 32, 64);
        x3 = (unsigned)__shfl_xor((int)c3, 32, 64);
        pl.u[0] = h ? x2 : c0;  pl.u[1] = h ? x3 : c1;
        pl.u[2] = h ? c2 : x0;  pl.u[3] = h ? c3 : x1;
      }
      const int kbv = mk * 64 + kp * 32 + 16 * h;
      const int vsw = (l31 & 7) << 4;
#pragma unroll
      for (int md = 0; md < 2; ++md) {
        const char* vrow = (const char*)Vbuf[p] + (md * 32 + l31) * 256;
        bf16x8 vh = *(const bf16x8*)(vrow + (kbv ^ vsw));
        bf16x8 vl = *(const bf16x8*)(vrow + 128 + (kbv ^ vsw));
        if (md == 0) {
          accA0 = mfma_bf16(vh, ph.v, accA0);
          accB0 = mfma_bf16(vh, pl.v, accB0);
          accB0 = mfma_bf16(vl, ph.v, accB0);
        } else {
          accA1 = mfma_bf16(vh, ph.v, accA1);
          accB1 = mfma_bf16(vh, pl.v, accB1);
          accB1 = mfma_bf16(vl, ph.v, accB1);
        }
      }
    }
    __syncthreads();                         // end barrier
  }

  // finalize: write O^T partials, l, m
  float* o = segO + (((size_t)bid * 2 + mk) * 2 + nq) * 2048;
#pragma unroll
  for (int md = 0; md < 2; ++md) {
#pragma unroll
    for (int r = 0; r < 16; ++r) {
      int d = md * 32 + (r & 3) + 8 * (r >> 2) + 4 * h;
      float val = md ? (accA1[r] + accB1[r]) : (accA0[r] + accB0[r]);
      o[d * 32 + l31] = val;
    }
  }
  if (lane < 32) segL[((size_t)bid * 2 + mk) * 64 + nq * 32 + l31] = lrun;
  if (mk == 0 && lane < 32) segM[(size_t)bid * 64 + nq * 32 + l31] = Mrun;
}

// ---------- combine: merge segments, normalize, transpose, write out ----------
__global__ __launch_bounds__(256) void combine_kernel(
    const float* __restrict__ segO, const float* __restrict__ segL,
    const float* __restrict__ segM, float* __restrict__ out)
{
  __shared__ float Ot[64 * 68];
  __shared__ float Ls[64];
  __shared__ float Sc[4][64];

  int bq = blockIdx.x;
  int b = bq >> 5, qt = bq & 31;
  int g4 = qt >> 3, nch = g4 + 1;
  int base4 = (g4 == 0) ? 0 : (g4 == 1) ? 8 : (g4 == 2) ? 24 : 48;
  int slot0 = b * 80 + base4 + (qt - g4 * 8) * nch;
  int tid = threadIdx.x;

  if (tid < 64) {
    float M = -3e38f;
    for (int c = 0; c < nch; ++c) M = fmaxf(M, segM[(size_t)(slot0 + c) * 64 + tid]);
    float L = 0.f;
    for (int c = 0; c < nch; ++c) {
      float s = __expf(segM[(size_t)(slot0 + c) * 64 + tid] - M);
      Sc[c][tid] = s;
      L += s * (segL[((size_t)(slot0 + c) * 2 + 0) * 64 + tid] +
                segL[((size_t)(slot0 + c) * 2 + 1) * 64 + tid]);
    }
    Ls[tid] = L;
  }
  __syncthreads();
  {
    int d = tid >> 2, q0 = (tid & 3) * 16;
    for (int qq = 0; qq < 16; ++qq) {
      int q = q0 + qq;
      float acc = 0.f;
      for (int c = 0; c < nch; ++c) {
        size_t s0 = (((size_t)(slot0 + c) * 2 + 0) * 2 + (q >> 5)) * 2048 + d * 32 + (q & 31);
        size_t s1 = (((size_t)(slot0 + c) * 2 + 1) * 2 + (q >> 5)) * 2048 + d * 32 + (q & 31);
        acc += Sc[c][q] * (segO[s0] + segO[s1]);
      }
      Ot[d * 68 + q] = acc;
    }
  }
  __syncthreads();
  {
    int q = tid >> 2, dd0 = (tid & 3) * 16;
    float inv = 1.f / Ls[q];
    float* dst = out + ((size_t)b * 2048 + qt * 64 + q) * 64 + dd0;
#pragma unroll
    for (int i = 0; i < 4; ++i) {
      float4 vv;
      vv.x = Ot[(dd0 + 4 * i + 0) * 68 + q] * inv;
      vv.y = Ot[(dd0 + 4 * i + 1) * 68 + q] * inv;
      vv.z = Ot[(dd0 + 4 * i + 2) * 68 + q] * inv;
      vv.w = Ot[(dd0 + 4 * i + 3) * 68 + q] * inv;
      *(float4*)(dst + 4 * i) = vv;
    }
  }
}

// ---------- launch ----------
extern "C" void kernel_launch(void* const* d_in, const int* in_sizes, int n_in,
                              void* d_out, int out_size, void* d_ws, size_t ws_size,
                              hipStream_t stream) {
  const float* x  = (const float*)d_in[0];
  const float* Wq = (const float*)d_in[1];
  const float* Wk = (const float*)d_in[2];
  const float* Wv = (const float*)d_in[3];

  char* wsb = (char*)d_ws;
  short* wth = (short*)(wsb + 0);
  short* wtl = (short*)(wsb + 393216);
  short* qh  = (short*)(wsb + 786432);
  short* ql  = (short*)(wsb + 2883584);
  short* kh  = (short*)(wsb + 4980736);
  short* kl  = (short*)(wsb + 7077888);
  short* vth = (short*)(wsb + 9175040);
  short* vtl = (short*)(wsb + 11272192);
  float* segO = (float*)(wsb + 13369344);             // 640*2*2*64*32 f32 = 20.97 MB
  float* segL = (float*)(wsb + 13369344 + 20971520);  // 640*2*64 f32
  float* segM = (float*)(wsb + 13369344 + 20971520 + 327680); // 640*64 f32

  wconv_kernel<<<192, 256, 0, stream>>>(Wq, Wk, Wv, wth, wtl);
  proj_kernel<<<256, 256, 0, stream>>>(x, wth, wtl, qh, ql, kh, kl, vth, vtl);
  attn_kernel<<<640, 256, 0, stream>>>(qh, ql, kh, kl, vth, vtl, segO, segL, segM);
  combine_kernel<<<256, 256, 0, stream>>>(segO, segL, segM, (float*)d_out);
}

// Round 3
// 99.048 us; speedup vs baseline: 2.8735x; 1.1032x over previous
//
#include <hip/hip_runtime.h>
#include <math.h>

typedef __attribute__((ext_vector_type(8))) short bf16x8;
typedef __attribute__((ext_vector_type(16))) float fx16;

#define SEQ 2048
#define HD 64

// ---------- helpers ----------
__device__ __forceinline__ unsigned f2bf_bits(float f){
  unsigned u = __float_as_uint(f);
  return (u + 0x7fffu + ((u >> 16) & 1u)) >> 16;   // RNE to bf16
}
__device__ __forceinline__ unsigned cvt_pk_bf16(float a, float b){
  unsigned r;
  asm("v_cvt_pk_bf16_f32 %0, %1, %2" : "=v"(r) : "v"(a), "v"(b));
  return r;  // [15:0]=bf16(a), [31:16]=bf16(b)
}
union U8 { bf16x8 v; short s[8]; unsigned u[4]; };

__device__ __forceinline__ fx16 mfma_bf16(bf16x8 a, bf16x8 b, fx16 c){
  return __builtin_amdgcn_mfma_f32_32x32x16_bf16(a, b, c, 0, 0, 0);
}
__device__ __forceinline__ fx16 fzero(){
  fx16 z;
#pragma unroll
  for (int i = 0; i < 16; ++i) z[i] = 0.f;
  return z;
}

// ---------- W -> MFMA B-fragment layout ----------
// group gid = (stage*6 + t)*2 + half, stage = c*4+ks (64 stages of k=16), t = n-tile (0..5).
// Each group: 64 lanes x 16B. Lane (l31,h): col n=t*32+l31, k = stage*16 + h*8 + i.
__global__ __launch_bounds__(256) void wconv_kernel(
    const float* __restrict__ Wq, const float* __restrict__ Wk, const float* __restrict__ Wv,
    short* __restrict__ wsB)
{
  int gid = blockIdx.x * 4 + (threadIdx.x >> 6);  // 0..767
  int lane = threadIdx.x & 63;
  int l31 = lane & 31, h = lane >> 5;
  int half = gid & 1;
  int rem = gid >> 1;            // stage*6 + t
  int t = rem % 6;
  int stage = rem / 6;           // 0..63
  int n = t * 32 + l31;
  int mat = n >> 6, col = n & 63;
  const float* W = (mat == 0) ? Wq : (mat == 1) ? Wk : Wv;
  int kbase = stage * 16 + h * 8;
  U8 o;
#pragma unroll
  for (int i = 0; i < 8; ++i) {
    float f = W[(size_t)(kbase + i) * 64 + col];
    unsigned hb = f2bf_bits(f);
    if (half == 0) o.s[i] = (short)hb;
    else {
      float hf = __uint_as_float(hb << 16);
      o.s[i] = (short)f2bf_bits(f - hf);
    }
  }
  *(bf16x8*)(wsB + (size_t)gid * 512 + lane * 8) = o.v;
}

// ---------- QKV projection: no LDS staging, no barriers; reg-pipelined ----------
// grid 256 (64 rows each), 256 thr (4 waves): m = w&1 (32-row tile), nset = (w>>1)*3.
__global__ __launch_bounds__(256, 2) void proj_kernel(
    const float* __restrict__ x, const short* __restrict__ wsB,
    short* __restrict__ qh, short* __restrict__ ql,
    short* __restrict__ kh, short* __restrict__ kl,
    short* __restrict__ vth, short* __restrict__ vtl)
{
  __shared__ float Vb[64 * 68];   // v transpose bounce (epilogue only)

  const int tid = threadIdx.x;
  const int lane = tid & 63, w = tid >> 6;
  const int l31 = lane & 31, h = lane >> 5;
  const int m = w & 1;
  const int nset = (w >> 1) * 3;
  const int row0 = blockIdx.x * 64;
  const size_t xrow = (size_t)(row0 + m * 32 + l31) * 1024;

  fx16 accP[3], accQ[3];
#pragma unroll
  for (int t = 0; t < 3; ++t) { accP[t] = fzero(); accQ[t] = fzero(); }

  float4 A0[4][2], A1[4][2];
  bf16x8 B0[6], B1[6];

#define LOADA(AB, C1)                                                   \
  {                                                                     \
    _Pragma("unroll")                                                   \
    for (int ks = 0; ks < 4; ++ks) {                                    \
      int k = (C1) * 64 + ks * 16 + h * 8;                              \
      AB[ks][0] = *(const float4*)(x + xrow + k);                       \
      AB[ks][1] = *(const float4*)(x + xrow + k + 4);                   \
    }                                                                   \
  }

#define LOADB(BB, SR)                                                   \
  {                                                                     \
    _Pragma("unroll")                                                   \
    for (int tt = 0; tt < 3; ++tt) {                                    \
      size_t g2 = ((size_t)(SR) * 6 + nset + tt) * 2;                   \
      BB[tt * 2 + 0] = *(const bf16x8*)(wsB + g2 * 512 + lane * 8);     \
      BB[tt * 2 + 1] = *(const bf16x8*)(wsB + (g2 + 1) * 512 + lane * 8);\
    }                                                                   \
  }

#define STEP(AF, BB)                                                    \
  {                                                                     \
    U8 ah, al;                                                          \
    float xf[8];                                                        \
    xf[0] = AF[0].x; xf[1] = AF[0].y; xf[2] = AF[0].z; xf[3] = AF[0].w; \
    xf[4] = AF[1].x; xf[5] = AF[1].y; xf[6] = AF[1].z; xf[7] = AF[1].w; \
    _Pragma("unroll")                                                   \
    for (int i = 0; i < 8; ++i) {                                       \
      unsigned hb = f2bf_bits(xf[i]);                                   \
      ah.s[i] = (short)hb;                                              \
      float hf = __uint_as_float(hb << 16);                             \
      al.s[i] = (short)f2bf_bits(xf[i] - hf);                           \
    }                                                                   \
    _Pragma("unroll")                                                   \
    for (int tt = 0; tt < 3; ++tt) {                                    \
      accP[tt] = mfma_bf16(ah.v, BB[tt * 2 + 0], accP[tt]);             \
      accQ[tt] = mfma_bf16(ah.v, BB[tt * 2 + 1], accQ[tt]);             \
      accQ[tt] = mfma_bf16(al.v, BB[tt * 2 + 0], accQ[tt]);             \
    }                                                                   \
  }

#define CHUNK(C, ACUR, ANEXT)                                           \
  {                                                                     \
    if ((C) < 15) LOADA(ANEXT, (C) + 1);                                \
    STEP(ACUR[0], B0); if ((C) * 4 + 2 < 64) LOADB(B0, (C) * 4 + 2);    \
    STEP(ACUR[1], B1); if ((C) * 4 + 3 < 64) LOADB(B1, (C) * 4 + 3);    \
    STEP(ACUR[2], B0); if ((C) * 4 + 4 < 64) LOADB(B0, (C) * 4 + 4);    \
    STEP(ACUR[3], B1); if ((C) * 4 + 5 < 64) LOADB(B1, (C) * 4 + 5);    \
  }

  LOADA(A0, 0);
  LOADB(B0, 0);
  LOADB(B1, 1);
  for (int c2 = 0; c2 < 8; ++c2) {
    CHUNK(2 * c2 + 0, A0, A1);
    CHUNK(2 * c2 + 1, A1, A0);
  }
#undef CHUNK
#undef STEP
#undef LOADB
#undef LOADA

  // epilogue: q,k direct hi/lo stores; v via LDS transpose bounce
#pragma unroll
  for (int t = 0; t < 3; ++t) {
    int nt = nset + t;
    int mat = nt >> 1;
    int colb = (nt & 1) * 32 + l31;
    if (mat < 2) {
      short* dh = (mat == 0) ? qh : kh;
      short* dl = (mat == 0) ? ql : kl;
#pragma unroll
      for (int r = 0; r < 16; ++r) {
        float f = accP[t][r] + accQ[t][r];
        int rowg = row0 + m * 32 + (r & 3) + 8 * (r >> 2) + 4 * h;
        unsigned hb = f2bf_bits(f);
        float hf = __uint_as_float(hb << 16);
        unsigned lb = f2bf_bits(f - hf);
        dh[(size_t)rowg * 64 + colb] = (short)hb;
        dl[(size_t)rowg * 64 + colb] = (short)lb;
      }
    } else {
#pragma unroll
      for (int r = 0; r < 16; ++r) {
        float f = accP[t][r] + accQ[t][r];
        int srel = m * 32 + (r & 3) + 8 * (r >> 2) + 4 * h;
        Vb[srel * 68 + (nt - 4) * 32 + l31] = f;
      }
    }
  }
  __syncthreads();
  {
    int d = tid >> 2, sc = (tid & 3) * 16;
    int bb = row0 >> 11, s0 = row0 & 2047;
    U8 hv0, hv1, lv0, lv1;
#pragma unroll
    for (int ss = 0; ss < 16; ++ss) {
      float f = Vb[(sc + ss) * 68 + d];
      unsigned hb = f2bf_bits(f);
      float hf = __uint_as_float(hb << 16);
      unsigned lb = f2bf_bits(f - hf);
      if (ss < 8) { hv0.s[ss] = (short)hb; lv0.s[ss] = (short)lb; }
      else        { hv1.s[ss - 8] = (short)hb; lv1.s[ss - 8] = (short)lb; }
    }
    size_t o = (size_t)(bb * 64 + d) * 2048 + s0 + sc;
    *(bf16x8*)(vth + o) = hv0.v;  *(bf16x8*)(vth + o + 8) = hv1.v;
    *(bf16x8*)(vtl + o) = lv0.v;  *(bf16x8*)(vtl + o + 8) = lv1.v;
  }
}

// ---------- Flash attention: Q-tile 128 (4 waves x 32 q-cols), K-step 64, in-wave softmax ----------
// grid 8*40=320 blocks (split-k chunks <=8 steps), 256 thr.
__global__ __launch_bounds__(256, 2) void attn_kernel(
    const short* __restrict__ qh, const short* __restrict__ ql,
    const short* __restrict__ kh, const short* __restrict__ kl,
    const short* __restrict__ vth, const short* __restrict__ vtl,
    float* __restrict__ segO, float* __restrict__ segL, float* __restrict__ segM)
{
  __shared__ short Kbuf[2][64 * 128];   // row=k-row: [hi 64 d | lo 64 d], XOR-swizzled
  __shared__ short Vbuf[2][64 * 128];   // row=d:     [hi 64 k | lo 64 k], XOR-swizzled

  const int bid = blockIdx.x;
  const int b = bid / 40;
  const int j = bid % 40;
  int qt, ch, nch;
  if (j < 4)       { nch = 1; qt = j;               ch = 0; }
  else if (j < 12) { nch = 2; qt = 4 + (j - 4) / 2; ch = (j - 4) % 2; }
  else if (j < 24) { nch = 3; qt = 8 + (j - 12) / 3; ch = (j - 12) % 3; }
  else             { nch = 4; qt = 12 + (j - 24) / 4; ch = (j - 24) % 4; }
  const int S = 2 * qt + 2;
  const int bs = S / nch, rem = S % nch;
  const int nsteps = bs + (ch < rem ? 1 : 0);
  const int kt0 = ch * bs + (ch < rem ? ch : rem);

  const int tid = threadIdx.x;
  const int lane = tid & 63, w = tid >> 6;
  const int l31 = lane & 31, h = lane >> 5;
  const int qabs = qt * 128 + w * 32 + l31;

  // Q B-frags (hoisted): B[kk=d][col=q]
  bf16x8 qf0[4], qf1[4];
  {
    size_t qrow = ((size_t)b * 2048 + qabs) * 64;
#pragma unroll
    for (int ds = 0; ds < 4; ++ds) {
      qf0[ds] = *(const bf16x8*)(qh + qrow + ds * 16 + 8 * h);
      qf1[ds] = *(const bf16x8*)(ql + qrow + ds * 16 + 8 * h);
    }
  }

  // staging constants
  const int slot = tid & 15;
  const int half = slot >> 3;
  const int sb = (slot & 7) << 4;
  const int rbase = tid >> 4;
  const int d0 = (sb ^ ((rbase & 7) << 4)) >> 1;
  const short* ksrc = half ? kl : kh;
  const short* vsrc = half ? vtl : vth;
  const int woff = rbase * 256 + half * 128 + sb;

  fx16 accA0 = fzero(), accA1 = fzero(), accB0 = fzero(), accB1 = fzero();
  float Mrun = -3e38f, lrun = 0.f;
  const int sw = (l31 & 7) << 4;

  bf16x8 kreg[4], vreg[4];
#pragma unroll
  for (int jj = 0; jj < 4; ++jj) {
    kreg[jj] = *(const bf16x8*)(ksrc + ((size_t)b * 2048 + (size_t)kt0 * 64 + rbase + 16 * jj) * 64 + d0);
    vreg[jj] = *(const bf16x8*)(vsrc + ((size_t)(b * 64 + rbase + 16 * jj)) * 2048 + kt0 * 64 + d0);
  }
#pragma unroll
  for (int jj = 0; jj < 4; ++jj) {
    *(bf16x8*)((char*)Kbuf[0] + woff + jj * 4096) = kreg[jj];
    *(bf16x8*)((char*)Vbuf[0] + woff + jj * 4096) = vreg[jj];
  }
  __syncthreads();

  for (int it = 0; it < nsteps; ++it) {
    const int kt = kt0 + it;
    const int p = it & 1;
    const bool hasnext = (it + 1 < nsteps);
    if (hasnext) {
      int kn = kt + 1;
#pragma unroll
      for (int jj = 0; jj < 4; ++jj) {
        kreg[jj] = *(const bf16x8*)(ksrc + ((size_t)b * 2048 + (size_t)kn * 64 + rbase + 16 * jj) * 64 + d0);
        vreg[jj] = *(const bf16x8*)(vsrc + ((size_t)(b * 64 + rbase + 16 * jj)) * 2048 + kn * 64 + d0);
      }
    }

#pragma unroll
    for (int ms = 0; ms < 2; ++ms) {
      // QK^T (swapped): S^T sub-tile 32k x 32q; A = K rows from LDS, B = Q frags
      fx16 stA = fzero(), stB = fzero(), stC = fzero();
      {
        const char* arow = (const char*)Kbuf[p] + (ms * 32 + l31) * 256;
#pragma unroll
        for (int ds = 0; ds < 4; ++ds) {
          const int kb = ds * 32 + 16 * h;
          bf16x8 ah = *(const bf16x8*)(arow + (kb ^ sw));
          bf16x8 al = *(const bf16x8*)(arow + 128 + (kb ^ sw));
          stA = mfma_bf16(ah, qf0[ds], stA);
          stB = mfma_bf16(ah, qf1[ds], stB);
          stC = mfma_bf16(al, qf0[ds], stC);
        }
      }
      float sv[16];
      const int kbase = kt * 64 + ms * 32;
      const bool diag = (kbase + 31 > qt * 128 + w * 32);   // wave-uniform
#pragma unroll
      for (int r = 0; r < 16; ++r) {
        float s = (stA[r] + stB[r] + stC[r]) * 0.125f;
        if (diag) {
          int ka = kbase + (r & 3) + 8 * (r >> 2) + 4 * h;
          if (ka > qabs) s = -3e38f;
        }
        sv[r] = s;
      }
      float tm = sv[0];
#pragma unroll
      for (int r = 1; r < 16; ++r) tm = fmaxf(tm, sv[r]);
      tm = fmaxf(tm, __shfl_xor(tm, 32, 64));
      float Mnew = fmaxf(Mrun, tm);
      float alpha = __expf(Mrun - Mnew);
      Mrun = Mnew;
      float pvv[16]; float psum = 0.f;
#pragma unroll
      for (int r = 0; r < 16; ++r) { pvv[r] = __expf(sv[r] - Mnew); psum += pvv[r]; }
      psum += __shfl_xor(psum, 32, 64);
      lrun = lrun * alpha + psum;
#pragma unroll
      for (int r = 0; r < 16; ++r) {
        accA0[r] *= alpha; accA1[r] *= alpha; accB0[r] *= alpha; accB1[r] *= alpha;
      }
      // P -> bf16 hi/lo packed dwords
      unsigned chv[8], clv[8];
#pragma unroll
      for (int q2 = 0; q2 < 8; ++q2) {
        unsigned c = cvt_pk_bf16(pvv[2 * q2], pvv[2 * q2 + 1]);
        chv[q2] = c;
        float f0 = __uint_as_float(c << 16);
        float f1 = __uint_as_float(c & 0xffff0000u);
        clv[q2] = cvt_pk_bf16(pvv[2 * q2] - f0, pvv[2 * q2 + 1] - f1);
      }
      // PV: O^T += V^T P^T
#pragma unroll
      for (int kp = 0; kp < 2; ++kp) {
        U8 ph, pl;
        {
          unsigned c0 = chv[4 * kp], c1 = chv[4 * kp + 1], c2 = chv[4 * kp + 2], c3 = chv[4 * kp + 3];
          unsigned x0 = (unsigned)__shfl_xor((int)c0, 32, 64);
          unsigned x1 = (unsigned)__shfl_xor((int)c1, 32, 64);
          unsigned x2 = (unsigned)__shfl_xor((int)c2, 32, 64);
          unsigned x3 = (unsigned)__shfl_xor((int)c3, 32, 64);
          ph.u[0] = h ? x2 : c0;  ph.u[1] = h ? x3 : c1;
          ph.u[2] = h ? c2 : x0;  ph.u[3] = h ? c3 : x1;
          c0 = clv[4 * kp]; c1 = clv[4 * kp + 1]; c2 = clv[4 * kp + 2]; c3 = clv[4 * kp + 3];
          x0 = (unsigned)__shfl_xor((int)c0, 32, 64);
          x1 = (unsigned)__shfl_xor((int)c1, 32, 64);
          x2 = (unsigned)__shfl_xor((int)c2, 32, 64);
          x3 = (unsigned)__shfl_xor((int)c3, 32, 64);
          pl.u[0] = h ? x2 : c0;  pl.u[1] = h ? x3 : c1;
          pl.u[2] = h ? c2 : x0;  pl.u[3] = h ? c3 : x1;
        }
        const int kbv = ms * 64 + kp * 32 + 16 * h;
#pragma unroll
        for (int md = 0; md < 2; ++md) {
          const char* vrow = (const char*)Vbuf[p] + (md * 32 + l31) * 256;
          bf16x8 vh = *(const bf16x8*)(vrow + (kbv ^ sw));
          bf16x8 vl = *(const bf16x8*)(vrow + 128 + (kbv ^ sw));
          if (md == 0) {
            accA0 = mfma_bf16(vh, ph.v, accA0);
            accB0 = mfma_bf16(vh, pl.v, accB0);
            accB0 = mfma_bf16(vl, ph.v, accB0);
          } else {
            accA1 = mfma_bf16(vh, ph.v, accA1);
            accB1 = mfma_bf16(vh, pl.v, accB1);
            accB1 = mfma_bf16(vl, ph.v, accB1);
          }
        }
      }
    } // ms

    if (hasnext) {
#pragma unroll
      for (int jj = 0; jj < 4; ++jj) {
        *(bf16x8*)((char*)Kbuf[p ^ 1] + woff + jj * 4096) = kreg[jj];
        *(bf16x8*)((char*)Vbuf[p ^ 1] + woff + jj * 4096) = vreg[jj];
      }
    }
    __syncthreads();
  }

  // write partials: O^T [64 d][128 q], plus l, m per q
  float* o = segO + (size_t)bid * (64 * 128);
#pragma unroll
  for (int md = 0; md < 2; ++md) {
#pragma unroll
    for (int r = 0; r < 16; ++r) {
      int d = md * 32 + (r & 3) + 8 * (r >> 2) + 4 * h;
      float val = md ? (accA1[r] + accB1[r]) : (accA0[r] + accB0[r]);
      o[d * 128 + w * 32 + l31] = val;
    }
  }
  if (h == 0) {
    segL[(size_t)bid * 128 + w * 32 + l31] = lrun;
    segM[(size_t)bid * 128 + w * 32 + l31] = Mrun;
  }
}

// ---------- combine: merge <=4 chunks, normalize, transpose, write out ----------
__global__ __launch_bounds__(256) void combine_kernel(
    const float* __restrict__ segO, const float* __restrict__ segL,
    const float* __restrict__ segM, float* __restrict__ out)
{
  __shared__ float Sc[4][128];
  __shared__ float Linv[128];
  __shared__ float Ot[64 * 132];

  const int bq = blockIdx.x;
  const int b = bq >> 4, qt = bq & 15;
  const int g = qt >> 2, nch = g + 1;
  const int base = (g == 0) ? qt
                 : (g == 1) ? 4 + (qt - 4) * 2
                 : (g == 2) ? 12 + (qt - 8) * 3
                 : 24 + (qt - 12) * 4;
  const int slot0 = b * 40 + base;
  const int tid = threadIdx.x;

  if (tid < 128) {
    const int q = tid;
    float M = -3e38f;
    for (int c = 0; c < nch; ++c)
      M = fmaxf(M, segM[(size_t)(slot0 + c) * 128 + q]);
    float L = 0.f;
    for (int c = 0; c < nch; ++c) {
      float s = __expf(segM[(size_t)(slot0 + c) * 128 + q] - M);
      Sc[c][q] = s;
      L += s * segL[(size_t)(slot0 + c) * 128 + q];
    }
    Linv[q] = 1.f / L;
  }
  __syncthreads();
  {
    const int dr = tid >> 5;
    const int qc = (tid & 31) * 4;
    for (int dd = dr; dd < 64; dd += 8) {
      float4 acc = {0.f, 0.f, 0.f, 0.f};
      for (int c = 0; c < nch; ++c) {
        float4 v = *(const float4*)(segO + (size_t)(slot0 + c) * 8192 + dd * 128 + qc);
        acc.x += Sc[c][qc + 0] * v.x;
        acc.y += Sc[c][qc + 1] * v.y;
        acc.z += Sc[c][qc + 2] * v.z;
        acc.w += Sc[c][qc + 3] * v.w;
      }
      *(float4*)&Ot[dd * 132 + qc] = acc;
    }
  }
  __syncthreads();
  {
    const int q = tid >> 1, dh = (tid & 1) * 32;
    const float inv = Linv[q];
    float* dst = out + ((size_t)b * 2048 + qt * 128 + q) * 64 + dh;
#pragma unroll
    for (int i = 0; i < 8; ++i) {
      float4 o;
      o.x = Ot[(dh + 4 * i + 0) * 132 + q] * inv;
      o.y = Ot[(dh + 4 * i + 1) * 132 + q] * inv;
      o.z = Ot[(dh + 4 * i + 2) * 132 + q] * inv;
      o.w = Ot[(dh + 4 * i + 3) * 132 + q] * inv;
      *(float4*)(dst + 4 * i) = o;
    }
  }
}

// ---------- launch ----------
extern "C" void kernel_launch(void* const* d_in, const int* in_sizes, int n_in,
                              void* d_out, int out_size, void* d_ws, size_t ws_size,
                              hipStream_t stream) {
  const float* x  = (const float*)d_in[0];
  const float* Wq = (const float*)d_in[1];
  const float* Wk = (const float*)d_in[2];
  const float* Wv = (const float*)d_in[3];

  char* wsb = (char*)d_ws;
  short* wsB = (short*)(wsb + 0);                     // 786432 B
  short* qh  = (short*)(wsb + 786432);
  short* ql  = (short*)(wsb + 2883584);
  short* kh  = (short*)(wsb + 4980736);
  short* kl  = (short*)(wsb + 7077888);
  short* vth = (short*)(wsb + 9175040);
  short* vtl = (short*)(wsb + 11272192);
  float* segO = (float*)(wsb + 13369344);             // 320*8192*4 = 10485760 B
  float* segL = (float*)(wsb + 23855104);             // 163840 B
  float* segM = (float*)(wsb + 24018944);             // 163840 B

  wconv_kernel<<<192, 256, 0, stream>>>(Wq, Wk, Wv, wsB);
  proj_kernel<<<256, 256, 0, stream>>>(x, wsB, qh, ql, kh, kl, vth, vtl);
  attn_kernel<<<320, 256, 0, stream>>>(qh, ql, kh, kl, vth, vtl, segO, segL, segM);
  combine_kernel<<<128, 256, 0, stream>>>(segO, segL, segM, (float*)d_out);
}